// Round 12
// baseline (503.675 us; speedup 1.0000x reference)
//
#include <hip/hip_runtime.h>
#include <hip/hip_bf16.h>

#define B_ 256
#define T_ 512
#define I_ 128
#define H_ 256

// 2*log2(e): W_ih, W_hh, bias pre-scaled so the scan accumulator holds
// s = 2*log2e*z and tanh(z) = 1 - 2/(1 + 2^s) needs no pre-multiply.
// ALL transcendentals via compiler builtins — inline-asm v_exp_f32 was the
// pinned corruption mechanism in EVERY failed round (R2-R5): the TRANS-op
// hazard recognizer cannot see inside asm strings. All builtin-only
// kernels (R9, R10, R11) passed, including R10's novel structure.
#define SC 2.885390081777927f

typedef __bf16 bf16x8 __attribute__((ext_vector_type(8)));
typedef float  f32x4  __attribute__((ext_vector_type(4)));
typedef unsigned short u16;
typedef unsigned int   u32;

union U16x8Cast { uint4 v; bf16x8 b; };

__device__ inline u16 f2b(float f) {           // fp32 -> bf16 bits (RNE)
    union { __bf16 h; u16 u; } c; c.h = (__bf16)f; return c.u;
}
__device__ inline bf16x8 pack8(float4 lo, float4 hi) {
    bf16x8 f;
    f[0]=(__bf16)lo.x; f[1]=(__bf16)lo.y; f[2]=(__bf16)lo.z; f[3]=(__bf16)lo.w;
    f[4]=(__bf16)hi.x; f[5]=(__bf16)hi.y; f[6]=(__bf16)hi.z; f[7]=(__bf16)hi.w;
    return f;
}
__device__ inline bf16x8 pack8s(float4 lo, float4 hi, float s) {
    bf16x8 f;
    f[0]=(__bf16)(lo.x*s); f[1]=(__bf16)(lo.y*s); f[2]=(__bf16)(lo.z*s); f[3]=(__bf16)(lo.w*s);
    f[4]=(__bf16)(hi.x*s); f[5]=(__bf16)(hi.y*s); f[6]=(__bf16)(hi.z*s); f[7]=(__bf16)(hi.w*s);
    return f;
}
__device__ inline uint2 pack4(float a, float b, float c, float d) {
    uint2 p;
    p.x = (u32)f2b(a) | ((u32)f2b(b) << 16);
    p.y = (u32)f2b(c) | ((u32)f2b(d) << 16);
    return p;
}
__device__ inline f32x4 b4_to_f32x4(uint2 u) {
    f32x4 r;
    r[0] = __uint_as_float(u.x << 16);
    r[1] = __uint_as_float(u.x & 0xFFFF0000u);
    r[2] = __uint_as_float(u.y << 16);
    r[3] = __uint_as_float(u.y & 0xFFFF0000u);
    return r;
}
// tanh from pre-scaled s = 2*log2e*z: tanh(z) = 1 - 2/(1 + 2^s).
// Builtins only (R9-verified). s->+inf: 1; s->-inf: -1. No NaN.
__device__ inline float tanh_pre(float s) {
    float e = __builtin_amdgcn_exp2f(s);
    float r = __builtin_amdgcn_rcpf(1.f + e);
    return fmaf(-2.f, r, 1.f);
}

// =====================================================================
// Kernel 1 (MFMA GEMM): xw[t][b][n] = SC * (x[bT+t,:]*W_ih[n,:] + bias)
// VERBATIM the R1/R9 128-row version (passed, 55us; R11's 64-row tile
// regressed to 71us — per-block W_ih-frag load cost doubled).
// =====================================================================
#define LDST 264
__global__ __launch_bounds__(256, 2) void xw_gemm_mfma(const float* __restrict__ x,
                                                       const float* __restrict__ W_ih,
                                                       const float* __restrict__ b_ih,
                                                       const float* __restrict__ b_hh,
                                                       u16* __restrict__ xw) {
    __shared__ u16 tile[64 * LDST];

    const int tid  = (int)threadIdx.x;
    const int wave = tid >> 6;
    const int lane = tid & 63;
    const int q    = lane >> 4;
    const int ml   = lane & 15;
    const int m0   = (int)blockIdx.x * 128;
    const int b    = m0 >> 9;
    const int t0   = m0 & 511;
    const int n0   = wave * 64;

    bf16x8 wA[4][4];
#pragma unroll
    for (int tau = 0; tau < 4; ++tau) {
        const float* wr = W_ih + (size_t)(n0 + tau * 16 + ml) * I_;
#pragma unroll
        for (int kap = 0; kap < 4; ++kap) {
            const int k0 = kap * 32 + q * 8;
            wA[tau][kap] = pack8s(*(const float4*)(wr + k0), *(const float4*)(wr + k0 + 4), SC);
        }
    }

    f32x4 acc[8][4];
#pragma unroll
    for (int mt = 0; mt < 8; ++mt)
#pragma unroll
        for (int tau = 0; tau < 4; ++tau) acc[mt][tau] = (f32x4)0.f;

#pragma unroll
    for (int kap = 0; kap < 4; ++kap) {
        bf16x8 xB[8];
#pragma unroll
        for (int mt = 0; mt < 8; ++mt) {
            const float* xr = x + (size_t)(m0 + mt * 16 + ml) * I_ + kap * 32 + q * 8;
            xB[mt] = pack8(*(const float4*)xr, *(const float4*)(xr + 4));
        }
#pragma unroll
        for (int mt = 0; mt < 8; ++mt)
#pragma unroll
            for (int tau = 0; tau < 4; ++tau)
                acc[mt][tau] = __builtin_amdgcn_mfma_f32_16x16x32_bf16(
                    wA[tau][kap], xB[mt], acc[mt][tau], 0, 0, 0);
    }

    float4 bias4[4];
#pragma unroll
    for (int tau = 0; tau < 4; ++tau) {
        const int n = n0 + tau * 16 + q * 4;
        float4 bi = *(const float4*)(b_ih + n);
        float4 bh = *(const float4*)(b_hh + n);
        bias4[tau] = make_float4((bi.x + bh.x) * SC, (bi.y + bh.y) * SC,
                                 (bi.z + bh.z) * SC, (bi.w + bh.w) * SC);
    }

#pragma unroll
    for (int p = 0; p < 2; ++p) {
        if (p) __syncthreads();
#pragma unroll
        for (int mt = 0; mt < 4; ++mt) {
            const int row = mt * 16 + ml;
            const int mg  = p * 4 + mt;
#pragma unroll
            for (int tau = 0; tau < 4; ++tau) {
                uint2 pk = pack4(acc[mg][tau][0] + bias4[tau].x,
                                 acc[mg][tau][1] + bias4[tau].y,
                                 acc[mg][tau][2] + bias4[tau].z,
                                 acc[mg][tau][3] + bias4[tau].w);
                *(uint2*)(tile + row * LDST + n0 + tau * 16 + q * 4) = pk;
            }
        }
        __syncthreads();
#pragma unroll
        for (int s = 0; s < 4; ++s) {
            const int rr = s * 16 + (tid >> 4);
            const int c  = tid & 15;
            const uint4* srcp = (const uint4*)(tile + rr * LDST);
            uint4* dstp = (uint4*)(xw + ((size_t)(t0 + p * 64 + rr) * B_ + b) * H_);
            uint4 v0 = srcp[c];
            uint4 v1 = srcp[c + 16];
            dstp[c] = v0;
            dstp[c + 16] = v1;
        }
    }
}

// =====================================================================
// Kernel 2 (MFMA scan) — barrier-free wave-skew scan, builtin-only.
// The R2/R3 protocol (audits always passed; failures now fully attributed
// to the asm-v_exp hazard present in every failed variant):
//  * wave w owns n-chunk and k-chunk w; produces chunk w of h each step.
//  * QUAD-buffered h: step t reads hbuf[t&3], writes hbuf[(t+1)&3].
//    Writer at step t has polled all flags >= t, so every wave is at
//    step >= t -> no reader touches (t+1)&3 (readers at t/t+1 use
//    t&3/(t+1)&3... writer targets the one slot no concurrent reader
//    uses; skew cap 1, buffer margin 2).
//  * flags via __hip_atomic_load(ACQUIRE)/store(RELEASE), WORKGROUP
//    scope, on __shared__ — compiler owns lgkmcnt fencing; release
//    drains the wave's ds_writes (lgkmcnt is wave-wide) before publish.
//  * pre-rotated wf (wf[tau2][i] = chunk (wave+i)&7) -> static indexing;
//    own chunk read poll-free; per-slot flag cache skips settled polls.
// No s_barrier in the loop: waves skew so one wave's tanh/pack (VALU)
// fills another wave's LDS-port slot — R10 proved this overlap is worth
// ~13%+ when port-saturated; here it comes without halving CU count.
// =====================================================================
__global__ __launch_bounds__(512, 1) void rnn_scan_mfma(const u16* __restrict__ xw,
                                                        const float* __restrict__ W_hh,
                                                        const float* __restrict__ fc_w,
                                                        const float* __restrict__ fc_b,
                                                        float* __restrict__ out) {
    __shared__ __attribute__((aligned(16))) u16 hbuf[4][4096];  // 4 x 8 KB
    __shared__ u32 hflag[8];
    __shared__ float red[8][16];

    const int tid  = (int)threadIdx.x;
    const int wave = tid >> 6;          // 0..7, owns n-chunk and k-chunk `wave`
    const int lane = tid & 63;
    const int q    = lane >> 4;
    const int m    = lane & 15;
    const int b0   = (int)blockIdx.x * 16;

    // W_hh A-frags (SC-scaled), PRE-ROTATED: wf[tau2][i] holds k-chunk
    // c=(wave+i)&7 so the step loop indexes wf statically while reading
    // chunks in rotation order own, w+1, ..., w+7.
    bf16x8 wf[2][8];
#pragma unroll
    for (int tau2 = 0; tau2 < 2; ++tau2) {
        const float* wr = W_hh + (size_t)(wave * 32 + tau2 * 16 + m) * H_;
#pragma unroll
        for (int i = 0; i < 8; ++i) {
            const int c  = (wave + i) & 7;
            const int k0 = c * 32 + q * 8;
            wf[tau2][i] = pack8s(*(const float4*)(wr + k0), *(const float4*)(wr + k0 + 4), SC);
        }
    }

    // LDS write indices (u16 units) for C -> B-frag relayout (own chunk)
    int widx[2];
#pragma unroll
    for (int tau2 = 0; tau2 < 2; ++tau2) {
        const int nbw = wave * 32 + tau2 * 16 + q * 4;
        widx[tau2] = (nbw >> 5) * 512 + (((nbw >> 3) & 3) * 16 + m) * 8 + (nbw & 7);
    }

    {   // zero h buffer 0 (8 KB = 512 uint4, 512 threads) + flags
        uint4* p = (uint4*)&hbuf[0][0];
        const uint4 z = {0u, 0u, 0u, 0u};
        p[tid] = z;
        if (tid < 8) hflag[tid] = 0;
    }
    __syncthreads();                    // only barrier before the fc head

    const u16* xwp = xw + (size_t)(b0 + m) * H_ + (wave * 32 + q * 4);
    const size_t tstride = (size_t)B_ * H_;

    uint2 pfA[2], pfB[2];               // alternating prefetch, never copied
    pfA[0] = *(const uint2*)(xwp);
    pfA[1] = *(const uint2*)(xwp + 16);
    pfB[0] = *(const uint2*)(xwp + tstride);
    pfB[1] = *(const uint2*)(xwp + tstride + 16);

    u32 flc[8];                         // last-observed flag per rotation slot
#pragma unroll
    for (int i = 0; i < 8; ++i) flc[i] = 0;

    f32x4 acc[2];

#define SCAN_STEP(T_CUR, PF, WRITE_OUT)                                        \
    {                                                                          \
        const int t_ = (T_CUR);                                                \
        acc[0] = b4_to_f32x4(PF[0]);                                           \
        acc[1] = b4_to_f32x4(PF[1]);                                           \
        if (t_ + 2 < T_) {                                                     \
            const u16* pt_ = xwp + (size_t)(t_ + 2) * tstride;                 \
            PF[0] = *(const uint2*)(pt_);                                      \
            PF[1] = *(const uint2*)(pt_ + 16);                                 \
        }                                                                      \
        const uint4* hb_ = (const uint4*)&hbuf[t_ & 3][0];                     \
        U16x8Cast cv[8];                                                       \
        cv[0].v = hb_[wave * 64 + lane];   /* own chunk: poll-free */          \
        _Pragma("unroll")                                                      \
        for (int i = 1; i < 8; ++i) {                                          \
            const int c_ = (wave + i) & 7;                                     \
            if (flc[i] < (u32)t_) {                                            \
                u32 f_;                                                        \
                do {                                                           \
                    f_ = __hip_atomic_load(&hflag[c_], __ATOMIC_ACQUIRE,       \
                                           __HIP_MEMORY_SCOPE_WORKGROUP);      \
                } while (f_ < (u32)t_);                                        \
                flc[i] = f_;                                                   \
            }                                                                  \
            cv[i].v = hb_[c_ * 64 + lane];                                     \
            acc[0] = __builtin_amdgcn_mfma_f32_16x16x32_bf16(                  \
                wf[0][i - 1], cv[i - 1].b, acc[0], 0, 0, 0);                   \
            acc[1] = __builtin_amdgcn_mfma_f32_16x16x32_bf16(                  \
                wf[1][i - 1], cv[i - 1].b, acc[1], 0, 0, 0);                   \
        }                                                                      \
        acc[0] = __builtin_amdgcn_mfma_f32_16x16x32_bf16(                      \
            wf[0][7], cv[7].b, acc[0], 0, 0, 0);                               \
        acc[1] = __builtin_amdgcn_mfma_f32_16x16x32_bf16(                      \
            wf[1][7], cv[7].b, acc[1], 0, 0, 0);                               \
        if (WRITE_OUT) {                                                       \
            u16* wb_ = &hbuf[(t_ + 1) & 3][0];                                 \
            _Pragma("unroll")                                                  \
            for (int tau2 = 0; tau2 < 2; ++tau2) {                             \
                uint2 pk_ = pack4(tanh_pre(acc[tau2][0]), tanh_pre(acc[tau2][1]), \
                                  tanh_pre(acc[tau2][2]), tanh_pre(acc[tau2][3])); \
                *(uint2*)(wb_ + widx[tau2]) = pk_;                             \
            }                                                                  \
            if (lane == 0)                                                     \
                __hip_atomic_store(&hflag[wave], (u32)(t_ + 1),                \
                                   __ATOMIC_RELEASE, __HIP_MEMORY_SCOPE_WORKGROUP); \
        }                                                                      \
    }

    for (int tt = 0; tt < T_ / 2; ++tt) {
        SCAN_STEP(2 * tt,     pfA, true);
        SCAN_STEP(2 * tt + 1, pfB, (2 * tt + 1) != (T_ - 1));
    }
#undef SCAN_STEP

    // fc head: out[b] = sum_n tanh(h)[n] * fc_w[n] + fc_b
    float4 fcw[2];
#pragma unroll
    for (int tau2 = 0; tau2 < 2; ++tau2)
        fcw[tau2] = *(const float4*)(fc_w + wave * 32 + tau2 * 16 + q * 4);

    float partial = 0.f;
#pragma unroll
    for (int tau2 = 0; tau2 < 2; ++tau2) {
        partial += tanh_pre(acc[tau2][0]) * fcw[tau2].x;
        partial += tanh_pre(acc[tau2][1]) * fcw[tau2].y;
        partial += tanh_pre(acc[tau2][2]) * fcw[tau2].z;
        partial += tanh_pre(acc[tau2][3]) * fcw[tau2].w;
    }
    partial += __shfl_xor(partial, 16);
    partial += __shfl_xor(partial, 32);
    __syncthreads();
    if (lane < 16) red[wave][m] = partial;
    __syncthreads();
    if (tid < 16) {
        float s = red[0][tid] + red[1][tid] + red[2][tid] + red[3][tid]
                + red[4][tid] + red[5][tid] + red[6][tid] + red[7][tid];
        out[b0 + tid] = s + fc_b[0];
    }
}

// =====================================================================
extern "C" void kernel_launch(void* const* d_in, const int* in_sizes, int n_in,
                              void* d_out, int out_size, void* d_ws, size_t ws_size,
                              hipStream_t stream) {
    const float* x    = (const float*)d_in[0];
    const float* W_ih = (const float*)d_in[1];
    const float* W_hh = (const float*)d_in[2];
    const float* b_ih = (const float*)d_in[3];
    const float* b_hh = (const float*)d_in[4];
    const float* fc_w = (const float*)d_in[5];
    const float* fc_b = (const float*)d_in[6];
    float* out = (float*)d_out;

    u16* xwbuf = (u16*)d_ws;                           // 64 MB bf16 [T][B][H]
    xw_gemm_mfma<<<(B_ * T_) / 128, 256, 0, stream>>>(x, W_ih, b_ih, b_hh, xwbuf);
    rnn_scan_mfma<<<B_ / 16, 512, 0, stream>>>(xwbuf, W_hh, fc_w, fc_b, out);
}